// Round 15
// baseline (247.194 us; speedup 1.0000x reference)
//
#include <hip/hip_runtime.h>
#include <hip/hip_bf16.h>
#include <math.h>

// TopK router: logits = x @ gate_w^T, softmax, top-2, renormalize.
// M=32768 tokens, K=4096, E=64 experts.
// Outputs (concat, harness reads whole buffer as float32):
//   d_out[0 .. 2M)  : top-2 weights (descending)
//   d_out[2M .. 4M) : top-2 expert indices, stored as float values
//
// R15: DRAM-burst fix. R5/R13/R14 all plateaued ~237us reading x as 128B
// pieces from ~32K concurrent row-streams (row-activation bound ~2.2TB/s;
// the 1KB-contiguous fill kernels hit 6.6TB/s). Now: chunk k=128 -> A tile
// [32 rows][512B] staged by 16x 1KB-contiguous global_load_lds (4x longer
// bursts), double-buffered, counted vmcnt(4) + raw barriers (T4). B stays
// register-loaded from L2-resident packed bf16 hi/lo (prep_b). Read-side
// LDS conflicts: XOR slot^(row&7) pre-applied on the GLOBAL source
// (involution, preserves 128B transaction sets) + same XOR on ds_read.
// Epilogue: proven top-3 + TAU=1e-4 + parallel fp64 refine.

typedef __attribute__((ext_vector_type(8))) short short8;
typedef __attribute__((ext_vector_type(4))) float f32x4;

#define TPB 32
#define NCH 32      // K/128 chunks
#define TAU 1e-4f
#define LROW 68

__device__ __forceinline__ void cvt8(const f32x4* v, short8* hi, short8* lo) {
    const float* f = reinterpret_cast<const float*>(v);
#pragma unroll
    for (int j = 0; j < 8; ++j) {
        __hip_bfloat16 h = __float2bfloat16(f[j]);
        float r = f[j] - __bfloat162float(h);
        __hip_bfloat16 l = __float2bfloat16(r);
        (*hi)[j] = (short)*reinterpret_cast<unsigned short*>(&h);
        (*lo)[j] = (short)*reinterpret_cast<unsigned short*>(&l);
    }
}

// Pack gw into MFMA-fragment order: entry (nt*8192 + w*64 + ln) = 8 bf16 of
// row nt*16+(ln&15), k = w*32 + (ln>>4)*8.
__global__ void prep_b(const float* __restrict__ gw,
                       short8* __restrict__ bh, short8* __restrict__ bl) {
    const int tid = blockIdx.x * 256 + threadIdx.x;
    const int ln  = tid & 63;
    const int w   = (tid >> 6) & 127;
    const int nt  = tid >> 13;
    const int row = nt * 16 + (ln & 15);
    const int k   = w * 32 + ((ln >> 4) << 3);
    f32x4 v[2];
    v[0] = *reinterpret_cast<const f32x4*>(gw + (long)row * 4096 + k);
    v[1] = *reinterpret_cast<const f32x4*>(gw + (long)row * 4096 + k + 4);
    short8 h, l;
    cvt8(v, &h, &l);
    bh[tid] = h;
    bl[tid] = l;
}

__device__ __forceinline__ void gload16(const void* g, void* l) {
    __builtin_amdgcn_global_load_lds(
        (const __attribute__((address_space(1))) void*)g,
        (__attribute__((address_space(3))) void*)l, 16, 0, 0);
}

// A LDS: [32 rows][512B] per buffer; buf0 @0, buf1 @16384.
// Wave wv stages instrs i=0..3 (global jj=wv*4+i); instr jj = rows 2jj,2jj+1
// = 1KB contiguous LDS at jj*1024, lane offset ln*16 (linear, DMA-legal).
#define STAGE(C, BUF) do {                                                    \
    char* aB = AB + (BUF) * 16384;                                            \
    _Pragma("unroll")                                                         \
    for (int i = 0; i < 4; ++i)                                               \
        gload16(srcA[i] + (long)(C) * 512, aB + (wv * 4 + i) * 1024 + ln * 16); \
} while (0)

__global__ __launch_bounds__(256, 4)
void router_fused(const float* __restrict__ x,
                  const short8* __restrict__ bhp,
                  const short8* __restrict__ blp,
                  const float* __restrict__ gw,
                  float* __restrict__ out,
                  int M, int K) {
    __shared__ __align__(16) char AB[32768];
    __shared__ int flags[TPB];
    __shared__ double Ld4[4][64];

    const int t  = threadIdx.x;
    const int wv = t >> 6;
    const int ln = t & 63;
    const int fr = ln & 15;
    const int q  = ln >> 4;
    const int mm = wv >> 1;                 // m-tile (16 tokens)
    const int nn = wv & 1;                  // n-half (32 experts)
    const long tok0 = (long)blockIdx.x * TPB;

    // A staging sources: instr i covers rows 2*(wv*4+i)+ (ln>>5); slot
    // (ln&31) pre-swizzled by row&7 within each 8-slot (128B) octet.
    const char* srcA[4];
#pragma unroll
    for (int i = 0; i < 4; ++i) {
        const int row  = 2 * (wv * 4 + i) + (ln >> 5);
        const int slot = (ln & 31);
        const int swz  = (slot & ~7) | ((slot & 7) ^ (row & 7));
        srcA[i] = (const char*)x + (tok0 + row) * (long)K * 4 + swz * 16;
    }

    f32x4 acc[2];
    acc[0] = (f32x4){0.f, 0.f, 0.f, 0.f};
    acc[1] = (f32x4){0.f, 0.f, 0.f, 0.f};

    STAGE(0, 0);
    STAGE(1, 1);

    const int R = mm * 16 + fr;             // A row this lane reads
    const int rk = R & 7;                   // swizzle key

    for (int c = 0; c < NCH; ++c) {
        const int buf = c & 1;
        if (c + 1 < NCH) asm volatile("s_waitcnt vmcnt(4)" ::: "memory");
        else             asm volatile("s_waitcnt vmcnt(0)" ::: "memory");
        __builtin_amdgcn_s_barrier();
        asm volatile("" ::: "memory");
        __builtin_amdgcn_sched_barrier(0);

        // ---- compute chunk c: 4 windows of k=32 ----
        {
            const char* aB = AB + buf * 16384 + R * 512;
#pragma unroll
            for (int w = 0; w < 4; ++w) {
                f32x4 av[2];
                av[0] = *(const f32x4*)(aB + (w * 8 + ((q * 2 + 0) ^ rk)) * 16);
                av[1] = *(const f32x4*)(aB + (w * 8 + ((q * 2 + 1) ^ rk)) * 16);
                short8 ah, al;
                cvt8(av, &ah, &al);
                const int widx = c * 4 + w;
#pragma unroll
                for (int ntl = 0; ntl < 2; ++ntl) {
                    const int nt = 2 * nn + ntl;
                    short8 bhv = bhp[nt * 8192 + widx * 64 + ln];
                    short8 blv = blp[nt * 8192 + widx * 64 + ln];
                    acc[ntl] = __builtin_amdgcn_mfma_f32_16x16x32_bf16(ah, bhv, acc[ntl], 0, 0, 0);
                    acc[ntl] = __builtin_amdgcn_mfma_f32_16x16x32_bf16(ah, blv, acc[ntl], 0, 0, 0);
                    acc[ntl] = __builtin_amdgcn_mfma_f32_16x16x32_bf16(al, bhv, acc[ntl], 0, 0, 0);
                    acc[ntl] = __builtin_amdgcn_mfma_f32_16x16x32_bf16(al, blv, acc[ntl], 0, 0, 0);
                }
            }
        }

        __builtin_amdgcn_sched_barrier(0);
        asm volatile("" ::: "memory");
        __builtin_amdgcn_s_barrier();       // all waves done reading buf
        asm volatile("" ::: "memory");
        if (c + 2 < NCH) STAGE(c + 2, buf);
        __builtin_amdgcn_sched_barrier(0);
    }

    // ---- epilogue: dump logits (C/D: col=lane&15, row=q*4+r) ----
    __syncthreads();
    float* Ls = (float*)AB;                 // loop done; alias A buffers
#pragma unroll
    for (int ntl = 0; ntl < 2; ++ntl)
#pragma unroll
        for (int r = 0; r < 4; ++r)
            Ls[(mm * 16 + q * 4 + r) * LROW + (2 * nn + ntl) * 16 + fr] = acc[ntl][r];
    __syncthreads();

    if (t < TPB) {
        const float* row = Ls + (long)t * LROW;
        float m1 = -INFINITY, m2 = -INFINITY, m3 = -INFINITY;
        int i1 = 0, i2 = 0;
#pragma unroll 8
        for (int e = 0; e < 64; ++e) {
            const float v = row[e];
            if (v > m1)      { m3 = m2; m2 = m1; i2 = i1; m1 = v; i1 = e; }
            else if (v > m2) { m3 = m2; m2 = v; i2 = e; }
            else if (v > m3) { m3 = v; }
        }
        const float e2 = expf(m2 - m1);
        const float s  = 1.0f + e2;

        const long g = tok0 + t;
        out[2 * g + 0] = 1.0f / s;
        out[2 * g + 1] = e2 / s;
        float* oi = out + 2 * (long)M;
        oi[2 * g + 0] = (float)i1;
        oi[2 * g + 1] = (float)i2;

        flags[t] = ((m1 - m2) < TAU) | ((m2 - m3) < TAU);
    }
    __syncthreads();

    // ---- fp64 refine, 256 threads cooperate (wave=K-quarter, lane=expert) ----
    for (int tk = 0; tk < TPB; ++tk) {
        if (flags[tk]) {
            const float* xr = x + (tok0 + tk) * (long)K + wv * 1024;
            const float* gr = gw + (long)ln * (long)K + wv * 1024;
            double s0 = 0.0, s1 = 0.0, s2 = 0.0, s3 = 0.0;
            for (int k = 0; k < 1024; k += 4) {
                const f32x4 a = *reinterpret_cast<const f32x4*>(xr + k);
                const f32x4 b = *reinterpret_cast<const f32x4*>(gr + k);
                s0 = fma((double)a.x, (double)b.x, s0);
                s1 = fma((double)a.y, (double)b.y, s1);
                s2 = fma((double)a.z, (double)b.z, s2);
                s3 = fma((double)a.w, (double)b.w, s3);
            }
            Ld4[wv][ln] = (s0 + s1) + (s2 + s3);
            __syncthreads();
            if (t == 0) {
                double m1 = -INFINITY, m2 = -INFINITY;
                int i1 = 0, i2 = 0;
                for (int e = 0; e < 64; ++e) {
                    const double v = Ld4[0][e] + Ld4[1][e] + Ld4[2][e] + Ld4[3][e];
                    if (v > m1)      { m2 = m1; i2 = i1; m1 = v; i1 = e; }
                    else if (v > m2) { m2 = v; i2 = e; }
                }
                const double e2 = exp(m2 - m1);
                const double s  = 1.0 + e2;
                const long g = tok0 + tk;
                out[2 * g + 0] = (float)(1.0 / s);
                out[2 * g + 1] = (float)(e2 / s);
                float* oi = out + 2 * (long)M;
                oi[2 * g + 0] = (float)i1;
                oi[2 * g + 1] = (float)i2;
            }
            __syncthreads();
        }
    }
}

extern "C" void kernel_launch(void* const* d_in, const int* in_sizes, int n_in,
                              void* d_out, int out_size, void* d_ws, size_t ws_size,
                              hipStream_t stream) {
    const float* x  = (const float*)d_in[0];
    const float* gw = (const float*)d_in[1];
    float* out = (float*)d_out;

    const int K = 4096;
    const int M = in_sizes[0] / K;          // 32768 tokens
    const int nblocks = M / TPB;            // 1024

    short8* bh = (short8*)d_ws;             // 1 MB packed B
    short8* bl = bh + 32768;

    prep_b<<<128, 256, 0, stream>>>(gw, bh, bl);
    router_fused<<<nblocks, 256, 0, stream>>>(x, bh, bl, gw, out, M, K);
}

// Round 16
// 233.079 us; speedup vs baseline: 1.0606x; 1.0606x over previous
//
#include <hip/hip_runtime.h>
#include <hip/hip_bf16.h>
#include <math.h>

// TopK router: logits = x @ gate_w^T, softmax, top-2, renormalize.
// M=32768 tokens, K=4096, E=64 experts.
// Outputs (concat, harness reads whole buffer as float32):
//   d_out[0 .. 2M)  : top-2 weights (descending)
//   d_out[2M .. 4M) : top-2 expert indices, stored as float values
//
// R16 = R15 + per-block K-PHASE STAGGER (single variable change).
// R5..R15 (five different mainloop structures) all plateau at ~240us
// (~2.2TB/s) while linear-address fills hit 6.6TB/s: all of them march K
// in lockstep over rows 16KB apart -> at any instant the chip reads a
// 512B-wide column of a 16KB-period matrix -> power-of-2 channel camping.
// Fix: block b starts its chunk ring at (b & 31) and wraps, so the 1024
// blocks cover all 32 K-phases simultaneously. Accumulation order per
// block changes (deterministic); noise ~1e-6 << TAU=1e-4.

typedef __attribute__((ext_vector_type(8))) short short8;
typedef __attribute__((ext_vector_type(4))) float f32x4;

#define TPB 32
#define NCH 32      // K/128 chunks
#define TAU 1e-4f
#define LROW 68

__device__ __forceinline__ void cvt8(const f32x4* v, short8* hi, short8* lo) {
    const float* f = reinterpret_cast<const float*>(v);
#pragma unroll
    for (int j = 0; j < 8; ++j) {
        __hip_bfloat16 h = __float2bfloat16(f[j]);
        float r = f[j] - __bfloat162float(h);
        __hip_bfloat16 l = __float2bfloat16(r);
        (*hi)[j] = (short)*reinterpret_cast<unsigned short*>(&h);
        (*lo)[j] = (short)*reinterpret_cast<unsigned short*>(&l);
    }
}

// Pack gw into MFMA-fragment order: entry (nt*8192 + w*64 + ln) = 8 bf16 of
// row nt*16+(ln&15), k = w*32 + (ln>>4)*8.
__global__ void prep_b(const float* __restrict__ gw,
                       short8* __restrict__ bh, short8* __restrict__ bl) {
    const int tid = blockIdx.x * 256 + threadIdx.x;
    const int ln  = tid & 63;
    const int w   = (tid >> 6) & 127;
    const int nt  = tid >> 13;
    const int row = nt * 16 + (ln & 15);
    const int k   = w * 32 + ((ln >> 4) << 3);
    f32x4 v[2];
    v[0] = *reinterpret_cast<const f32x4*>(gw + (long)row * 4096 + k);
    v[1] = *reinterpret_cast<const f32x4*>(gw + (long)row * 4096 + k + 4);
    short8 h, l;
    cvt8(v, &h, &l);
    bh[tid] = h;
    bl[tid] = l;
}

__device__ __forceinline__ void gload16(const void* g, void* l) {
    __builtin_amdgcn_global_load_lds(
        (const __attribute__((address_space(1))) void*)g,
        (__attribute__((address_space(3))) void*)l, 16, 0, 0);
}

// A LDS: [32 rows][512B] per buffer; buf0 @0, buf1 @16384.
#define STAGE(C, BUF) do {                                                    \
    char* aB = AB + (BUF) * 16384;                                            \
    _Pragma("unroll")                                                         \
    for (int i = 0; i < 4; ++i)                                               \
        gload16(srcA[i] + (long)(C) * 512, aB + (wv * 4 + i) * 1024 + ln * 16); \
} while (0)

__global__ __launch_bounds__(256, 4)
void router_fused(const float* __restrict__ x,
                  const short8* __restrict__ bhp,
                  const short8* __restrict__ blp,
                  const float* __restrict__ gw,
                  float* __restrict__ out,
                  int M, int K) {
    __shared__ __align__(16) char AB[32768];
    __shared__ int flags[TPB];
    __shared__ double Ld4[4][64];

    const int t  = threadIdx.x;
    const int wv = t >> 6;
    const int ln = t & 63;
    const int fr = ln & 15;
    const int q  = ln >> 4;
    const int mm = wv >> 1;                 // m-tile (16 tokens)
    const int nn = wv & 1;                  // n-half (32 experts)
    const long tok0 = (long)blockIdx.x * TPB;
    const int phase = blockIdx.x & (NCH - 1);   // K-phase stagger

    // A staging sources: instr i covers rows 2*(wv*4+i)+(ln>>5); slot
    // (ln&31) pre-swizzled by row&7 within each 8-slot (128B) octet.
    const char* srcA[4];
#pragma unroll
    for (int i = 0; i < 4; ++i) {
        const int row  = 2 * (wv * 4 + i) + (ln >> 5);
        const int slot = (ln & 31);
        const int swz  = (slot & ~7) | ((slot & 7) ^ (row & 7));
        srcA[i] = (const char*)x + (tok0 + row) * (long)K * 4 + swz * 16;
    }

    f32x4 acc[2];
    acc[0] = (f32x4){0.f, 0.f, 0.f, 0.f};
    acc[1] = (f32x4){0.f, 0.f, 0.f, 0.f};

    STAGE(phase, 0);
    STAGE((phase + 1) & (NCH - 1), 1);

    const int R = mm * 16 + fr;             // A row this lane reads
    const int rk = R & 7;                   // swizzle key

    for (int j = 0; j < NCH; ++j) {
        const int c   = (phase + j) & (NCH - 1);
        const int buf = j & 1;
        if (j + 1 < NCH) asm volatile("s_waitcnt vmcnt(4)" ::: "memory");
        else             asm volatile("s_waitcnt vmcnt(0)" ::: "memory");
        __builtin_amdgcn_s_barrier();
        asm volatile("" ::: "memory");
        __builtin_amdgcn_sched_barrier(0);

        // ---- compute chunk c: 4 windows of k=32 ----
        {
            const char* aB = AB + buf * 16384 + R * 512;
#pragma unroll
            for (int w = 0; w < 4; ++w) {
                f32x4 av[2];
                av[0] = *(const f32x4*)(aB + (w * 8 + ((q * 2 + 0) ^ rk)) * 16);
                av[1] = *(const f32x4*)(aB + (w * 8 + ((q * 2 + 1) ^ rk)) * 16);
                short8 ah, al;
                cvt8(av, &ah, &al);
                const int widx = c * 4 + w;
#pragma unroll
                for (int ntl = 0; ntl < 2; ++ntl) {
                    const int nt = 2 * nn + ntl;
                    short8 bhv = bhp[nt * 8192 + widx * 64 + ln];
                    short8 blv = blp[nt * 8192 + widx * 64 + ln];
                    acc[ntl] = __builtin_amdgcn_mfma_f32_16x16x32_bf16(ah, bhv, acc[ntl], 0, 0, 0);
                    acc[ntl] = __builtin_amdgcn_mfma_f32_16x16x32_bf16(ah, blv, acc[ntl], 0, 0, 0);
                    acc[ntl] = __builtin_amdgcn_mfma_f32_16x16x32_bf16(al, bhv, acc[ntl], 0, 0, 0);
                    acc[ntl] = __builtin_amdgcn_mfma_f32_16x16x32_bf16(al, blv, acc[ntl], 0, 0, 0);
                }
            }
        }

        __builtin_amdgcn_sched_barrier(0);
        asm volatile("" ::: "memory");
        __builtin_amdgcn_s_barrier();       // all waves done reading buf
        asm volatile("" ::: "memory");
        if (j + 2 < NCH) STAGE((phase + j + 2) & (NCH - 1), buf);
        __builtin_amdgcn_sched_barrier(0);
    }

    // ---- epilogue: dump logits (C/D: col=lane&15, row=q*4+r) ----
    __syncthreads();
    float* Ls = (float*)AB;                 // loop done; alias A buffers
#pragma unroll
    for (int ntl = 0; ntl < 2; ++ntl)
#pragma unroll
        for (int r = 0; r < 4; ++r)
            Ls[(mm * 16 + q * 4 + r) * LROW + (2 * nn + ntl) * 16 + fr] = acc[ntl][r];
    __syncthreads();

    if (t < TPB) {
        const float* row = Ls + (long)t * LROW;
        float m1 = -INFINITY, m2 = -INFINITY, m3 = -INFINITY;
        int i1 = 0, i2 = 0;
#pragma unroll 8
        for (int e = 0; e < 64; ++e) {
            const float v = row[e];
            if (v > m1)      { m3 = m2; m2 = m1; i2 = i1; m1 = v; i1 = e; }
            else if (v > m2) { m3 = m2; m2 = v; i2 = e; }
            else if (v > m3) { m3 = v; }
        }
        const float e2 = expf(m2 - m1);
        const float s  = 1.0f + e2;

        const long g = tok0 + t;
        out[2 * g + 0] = 1.0f / s;
        out[2 * g + 1] = e2 / s;
        float* oi = out + 2 * (long)M;
        oi[2 * g + 0] = (float)i1;
        oi[2 * g + 1] = (float)i2;

        flags[t] = ((m1 - m2) < TAU) | ((m2 - m3) < TAU);
    }
    __syncthreads();

    // ---- fp64 refine, 256 threads cooperate (wave=K-quarter, lane=expert) ----
    for (int tk = 0; tk < TPB; ++tk) {
        if (flags[tk]) {
            const float* xr = x + (tok0 + tk) * (long)K + wv * 1024;
            const float* gr = gw + (long)ln * (long)K + wv * 1024;
            double s0 = 0.0, s1 = 0.0, s2 = 0.0, s3 = 0.0;
            for (int k = 0; k < 1024; k += 4) {
                const f32x4 a = *reinterpret_cast<const f32x4*>(xr + k);
                const f32x4 b = *reinterpret_cast<const f32x4*>(gr + k);
                s0 = fma((double)a.x, (double)b.x, s0);
                s1 = fma((double)a.y, (double)b.y, s1);
                s2 = fma((double)a.z, (double)b.z, s2);
                s3 = fma((double)a.w, (double)b.w, s3);
            }
            Ld4[wv][ln] = (s0 + s1) + (s2 + s3);
            __syncthreads();
            if (t == 0) {
                double m1 = -INFINITY, m2 = -INFINITY;
                int i1 = 0, i2 = 0;
                for (int e = 0; e < 64; ++e) {
                    const double v = Ld4[0][e] + Ld4[1][e] + Ld4[2][e] + Ld4[3][e];
                    if (v > m1)      { m2 = m1; i2 = i1; m1 = v; i1 = e; }
                    else if (v > m2) { m2 = v; i2 = e; }
                }
                const double e2 = exp(m2 - m1);
                const double s  = 1.0 + e2;
                const long g = tok0 + tk;
                out[2 * g + 0] = (float)(1.0 / s);
                out[2 * g + 1] = (float)(e2 / s);
                float* oi = out + 2 * (long)M;
                oi[2 * g + 0] = (float)i1;
                oi[2 * g + 1] = (float)i2;
            }
            __syncthreads();
        }
    }
}

extern "C" void kernel_launch(void* const* d_in, const int* in_sizes, int n_in,
                              void* d_out, int out_size, void* d_ws, size_t ws_size,
                              hipStream_t stream) {
    const float* x  = (const float*)d_in[0];
    const float* gw = (const float*)d_in[1];
    float* out = (float*)d_out;

    const int K = 4096;
    const int M = in_sizes[0] / K;          // 32768 tokens
    const int nblocks = M / TPB;            // 1024

    short8* bh = (short8*)d_ws;             // 1 MB packed B
    short8* bl = bh + 32768;

    prep_b<<<128, 256, 0, stream>>>(gw, bh, bl);
    router_fused<<<nblocks, 256, 0, stream>>>(x, bh, bl, gw, out, M, K);
}